// Round 2
// baseline (669.389 us; speedup 1.0000x reference)
//
#include <hip/hip_runtime.h>

#define BS   8192
#define DIM  1024
#define TINV 10.0f    // 1 / TEMPERATURE
#define MARGIN 1.0f   // max(0.01, 1.0 - 0.1*0.0)

#define BM 128
#define BN 128
#define BK 64

typedef __attribute__((ext_vector_type(8))) short short8;
typedef __attribute__((ext_vector_type(4))) float f32x4;

__device__ __forceinline__ unsigned short f2bf(float f) {
    union { float f; unsigned int u; } v; v.f = f;
    unsigned int r = v.u + 0x7FFF + ((v.u >> 16) & 1);  // RNE
    return (unsigned short)(r >> 16);
}

// ---------------- Kernel 1: L2-normalize rows, emit bf16 A/N and posdist ----
__global__ __launch_bounds__(256) void normalize_kernel(
    const float* __restrict__ feat,
    unsigned short* __restrict__ Abf,
    unsigned short* __restrict__ Nbf,
    float* __restrict__ posdist)
{
    const int row  = blockIdx.x;
    const int tid  = threadIdx.x;
    const int lane = tid & 63;
    const int w    = tid >> 6;
    __shared__ float red[4][4];

    const float4* fo = (const float4*)(feat + (size_t)row * DIM);
    const float4* fp = (const float4*)(feat + (size_t)(BS + row) * DIM);
    const float4* fn = (const float4*)(feat + (size_t)(2 * BS + row) * DIM);
    float4 o = fo[tid], p = fp[tid], n = fn[tid];

    float so = o.x*o.x + o.y*o.y + o.z*o.z + o.w*o.w;
    float sp = p.x*p.x + p.y*p.y + p.z*p.z + p.w*p.w;
    float sn = n.x*n.x + n.y*n.y + n.z*n.z + n.w*n.w;
    #pragma unroll
    for (int off = 1; off < 64; off <<= 1) {
        so += __shfl_xor(so, off);
        sp += __shfl_xor(sp, off);
        sn += __shfl_xor(sn, off);
    }
    if (lane == 0) { red[w][0] = so; red[w][1] = sp; red[w][2] = sn; }
    __syncthreads();
    so = red[0][0] + red[1][0] + red[2][0] + red[3][0];
    sp = red[0][1] + red[1][1] + red[2][1] + red[3][1];
    sn = red[0][2] + red[1][2] + red[2][2] + red[3][2];

    const float io  = 1.0f / fmaxf(sqrtf(so), 1e-12f);
    const float ip  = 1.0f / fmaxf(sqrtf(sp), 1e-12f);
    const float in_ = 1.0f / fmaxf(sqrtf(sn), 1e-12f);

    float ax = o.x*io, ay = o.y*io, az = o.z*io, aw = o.w*io;
    float px = p.x*ip, py = p.y*ip, pz = p.z*ip, pw = p.w*ip;
    float nx = n.x*in_, ny = n.y*in_, nz = n.z*in_, nw = n.w*in_;

    ushort4 av; av.x = f2bf(ax); av.y = f2bf(ay); av.z = f2bf(az); av.w = f2bf(aw);
    ushort4 nv; nv.x = f2bf(nx); nv.y = f2bf(ny); nv.z = f2bf(nz); nv.w = f2bf(nw);
    ((ushort4*)(Abf + (size_t)row * DIM))[tid] = av;
    ((ushort4*)(Nbf + (size_t)row * DIM))[tid] = nv;

    float dx = ax - px, dy = ay - py, dz = az - pz, dw = aw - pw;
    float d = dx*dx + dy*dy + dz*dz + dw*dw;
    #pragma unroll
    for (int off = 1; off < 64; off <<= 1) d += __shfl_xor(d, off);
    if (lane == 0) red[w][3] = d;   // col 3: disjoint from cols 0..2 read above
    __syncthreads();
    if (tid == 0)
        posdist[row] = (red[0][3] + red[1][3] + red[2][3] + red[3][3]) * TINV;
}

// ---------------- Kernel 2: bf16 MFMA max-GEMM (C = A . N^T, row-max) -------
__global__ __launch_bounds__(256) void maxgemm_kernel(
    const unsigned short* __restrict__ Abf,
    const unsigned short* __restrict__ Nbf,
    float* __restrict__ partial)   // [BS][128] row-major
{
    __shared__ unsigned short As[BM * BK];
    __shared__ unsigned short Bs[BN * BK];

    const int tid  = threadIdx.x;
    const int lane = tid & 63;
    const int w    = tid >> 6;
    const int wm   = w >> 1, wn = w & 1;
    const int rowBase = blockIdx.y * BM;
    const int colBase = blockIdx.x * BN;

    const int lrow = lane >> 3;          // 0..7 : row within 8-row staging slab
    const int lcol = (lane & 7) * 8;     // 0..56: bf16 col offset (8 elems = 16B)

    const unsigned short* Ag = Abf + (size_t)rowBase * DIM;
    const unsigned short* Bg = Nbf + (size_t)colBase * DIM;

    f32x4 acc[4][4];
    #pragma unroll
    for (int i = 0; i < 4; i++)
        #pragma unroll
        for (int j = 0; j < 4; j++)
            acc[i][j] = (f32x4){0.f, 0.f, 0.f, 0.f};

    for (int k0 = 0; k0 < DIM; k0 += BK) {
        __syncthreads();  // prior iter's LDS reads done
        #pragma unroll
        for (int c = 0; c < 4; c++) {
            const int r0 = (w * 4 + c) * 8;   // 8-row slab; wave-uniform
            __builtin_amdgcn_global_load_lds(
                (const __attribute__((address_space(1))) void*)
                    (Ag + (size_t)(r0 + lrow) * DIM + k0 + lcol),
                (__attribute__((address_space(3))) void*)(As + r0 * BK),
                16, 0, 0);
            __builtin_amdgcn_global_load_lds(
                (const __attribute__((address_space(1))) void*)
                    (Bg + (size_t)(r0 + lrow) * DIM + k0 + lcol),
                (__attribute__((address_space(3))) void*)(Bs + r0 * BK),
                16, 0, 0);
        }
        __syncthreads();  // vmcnt drained by barrier semantics

        #pragma unroll
        for (int kk = 0; kk < BK; kk += 32) {
            short8 af[4], bfr[4];
            #pragma unroll
            for (int i = 0; i < 4; i++) {
                const int ar = wm * 64 + i * 16 + (lane & 15);
                af[i]  = *(const short8*)&As[ar * BK + kk + ((lane >> 4) * 8)];
                const int br = wn * 64 + i * 16 + (lane & 15);
                bfr[i] = *(const short8*)&Bs[br * BK + kk + ((lane >> 4) * 8)];
            }
            #pragma unroll
            for (int i = 0; i < 4; i++)
                #pragma unroll
                for (int j = 0; j < 4; j++)
                    acc[i][j] = __builtin_amdgcn_mfma_f32_16x16x32_bf16(
                        af[i], bfr[j], acc[i][j], 0, 0, 0);
        }
    }

    // Epilogue: per-row max over this wave's 64 columns, write one stripe value.
    // C/D layout (verified m89/m91): col = lane&15, row = (lane>>4)*4 + reg.
    const int stripe = blockIdx.x * 2 + wn;
    #pragma unroll
    for (int i = 0; i < 4; i++) {
        #pragma unroll
        for (int r = 0; r < 4; r++) {
            float v = fmaxf(fmaxf(acc[i][0][r], acc[i][1][r]),
                            fmaxf(acc[i][2][r], acc[i][3][r]));
            v = fmaxf(v, __shfl_xor(v, 1));
            v = fmaxf(v, __shfl_xor(v, 2));
            v = fmaxf(v, __shfl_xor(v, 4));
            v = fmaxf(v, __shfl_xor(v, 8));
            if ((lane & 15) == 0) {
                const int row = rowBase + wm * 64 + i * 16 + (lane >> 4) * 4 + r;
                partial[(size_t)row * 128 + stripe] = v;
            }
        }
    }
}

// ---------------- Kernel 3: stripe-max -> loss terms -> global sums ---------
__global__ __launch_bounds__(256) void reduce_kernel(
    const float* __restrict__ partial,
    const float* __restrict__ posdist,
    float* __restrict__ accum)
{
    const int tid  = threadIdx.x;
    const int lane = tid & 63;
    const int w    = tid >> 6;
    const int row  = blockIdx.x * 4 + w;

    float v = fmaxf(partial[(size_t)row * 128 + lane],
                    partial[(size_t)row * 128 + 64 + lane]);
    #pragma unroll
    for (int off = 1; off < 64; off <<= 1) v = fmaxf(v, __shfl_xor(v, off));

    if (lane == 0) {
        const float hard = (2.0f - 2.0f * v) * TINV;
        const float pos  = posdist[row];
        const float lossterm = fmaxf(MARGIN + pos - hard, 0.0f);
        atomicAdd(&accum[0], lossterm);
        atomicAdd(&accum[1], pos);
        atomicAdd(&accum[2], hard);
    }
}

// ---------------- Kernel 4: finalize means ----------------------------------
__global__ void finalize_kernel(const float* __restrict__ accum,
                                float* __restrict__ out)
{
    if (threadIdx.x == 0) {
        const float inv = 1.0f / (float)BS;
        out[0] = accum[0] * inv;
        out[1] = accum[1] * inv;
        out[2] = accum[2] * inv;
    }
}

extern "C" void kernel_launch(void* const* d_in, const int* in_sizes, int n_in,
                              void* d_out, int out_size, void* d_ws, size_t ws_size,
                              hipStream_t stream) {
    const float* feat = (const float*)d_in[0];
    char* ws = (char*)d_ws;

    // ws layout: Abf 16MiB | Nbf 16MiB | partial 4MiB | posdist 32KiB | accum
    unsigned short* Abf     = (unsigned short*)ws;
    unsigned short* Nbf     = (unsigned short*)(ws + ((size_t)16 << 20));
    float*          partial = (float*)(ws + ((size_t)32 << 20));
    float*          posdist = (float*)(ws + ((size_t)36 << 20));
    float*          accum   = (float*)(ws + ((size_t)36 << 20) + 32768);

    (void)hipMemsetAsync(accum, 0, 3 * sizeof(float), stream);

    normalize_kernel<<<BS, 256, 0, stream>>>(feat, Abf, Nbf, posdist);

    maxgemm_kernel<<<dim3(BS / BN, BS / BM), 256, 0, stream>>>(Abf, Nbf, partial);

    reduce_kernel<<<BS / 4, 256, 0, stream>>>(partial, posdist, accum);
    finalize_kernel<<<1, 64, 0, stream>>>(accum, (float*)d_out);
}

// Round 3
// 369.642 us; speedup vs baseline: 1.8109x; 1.8109x over previous
//
#include <hip/hip_runtime.h>

#define BS   8192
#define DIM  1024
#define TINV 10.0f    // 1 / TEMPERATURE
#define MARGIN 1.0f   // max(0.01, 1.0 - 0.1*0.0)

#define BM 128
#define BN 128
#define BK 64

typedef __attribute__((ext_vector_type(8))) short short8;
typedef __attribute__((ext_vector_type(4))) float f32x4;

__device__ __forceinline__ unsigned short f2bf(float f) {
    union { float f; unsigned int u; } v; v.f = f;
    unsigned int r = v.u + 0x7FFF + ((v.u >> 16) & 1);  // RNE
    return (unsigned short)(r >> 16);
}

// ---------------- Kernel 1: L2-normalize rows, emit bf16 A/N and posdist ----
__global__ __launch_bounds__(256) void normalize_kernel(
    const float* __restrict__ feat,
    unsigned short* __restrict__ Abf,
    unsigned short* __restrict__ Nbf,
    float* __restrict__ posdist)
{
    const int row  = blockIdx.x;
    const int tid  = threadIdx.x;
    const int lane = tid & 63;
    const int w    = tid >> 6;
    __shared__ float red[4][4];

    const float4* fo = (const float4*)(feat + (size_t)row * DIM);
    const float4* fp = (const float4*)(feat + (size_t)(BS + row) * DIM);
    const float4* fn = (const float4*)(feat + (size_t)(2 * BS + row) * DIM);
    float4 o = fo[tid], p = fp[tid], n = fn[tid];

    float so = o.x*o.x + o.y*o.y + o.z*o.z + o.w*o.w;
    float sp = p.x*p.x + p.y*p.y + p.z*p.z + p.w*p.w;
    float sn = n.x*n.x + n.y*n.y + n.z*n.z + n.w*n.w;
    #pragma unroll
    for (int off = 1; off < 64; off <<= 1) {
        so += __shfl_xor(so, off);
        sp += __shfl_xor(sp, off);
        sn += __shfl_xor(sn, off);
    }
    if (lane == 0) { red[w][0] = so; red[w][1] = sp; red[w][2] = sn; }
    __syncthreads();
    so = red[0][0] + red[1][0] + red[2][0] + red[3][0];
    sp = red[0][1] + red[1][1] + red[2][1] + red[3][1];
    sn = red[0][2] + red[1][2] + red[2][2] + red[3][2];

    const float io  = 1.0f / fmaxf(sqrtf(so), 1e-12f);
    const float ip  = 1.0f / fmaxf(sqrtf(sp), 1e-12f);
    const float in_ = 1.0f / fmaxf(sqrtf(sn), 1e-12f);

    float ax = o.x*io, ay = o.y*io, az = o.z*io, aw = o.w*io;
    float px = p.x*ip, py = p.y*ip, pz = p.z*ip, pw = p.w*ip;
    float nx = n.x*in_, ny = n.y*in_, nz = n.z*in_, nw = n.w*in_;

    ushort4 av; av.x = f2bf(ax); av.y = f2bf(ay); av.z = f2bf(az); av.w = f2bf(aw);
    ushort4 nv; nv.x = f2bf(nx); nv.y = f2bf(ny); nv.z = f2bf(nz); nv.w = f2bf(nw);
    ((ushort4*)(Abf + (size_t)row * DIM))[tid] = av;
    ((ushort4*)(Nbf + (size_t)row * DIM))[tid] = nv;

    float dx = ax - px, dy = ay - py, dz = az - pz, dw = aw - pw;
    float d = dx*dx + dy*dy + dz*dz + dw*dw;
    #pragma unroll
    for (int off = 1; off < 64; off <<= 1) d += __shfl_xor(d, off);
    if (lane == 0) red[w][3] = d;   // col 3: disjoint from cols 0..2 read above
    __syncthreads();
    if (tid == 0)
        posdist[row] = (red[0][3] + red[1][3] + red[2][3] + red[3][3]) * TINV;
}

// ---------------- Kernel 2: bf16 MFMA max-GEMM (C = A . N^T, row-max) -------
__global__ __launch_bounds__(256) void maxgemm_kernel(
    const unsigned short* __restrict__ Abf,
    const unsigned short* __restrict__ Nbf,
    float* __restrict__ partial)   // [BS][128] row-major
{
    __shared__ unsigned short As[BM * BK];
    __shared__ unsigned short Bs[BN * BK];

    const int tid  = threadIdx.x;
    const int lane = tid & 63;
    const int w    = tid >> 6;
    const int wm   = w >> 1, wn = w & 1;
    const int rowBase = blockIdx.y * BM;
    const int colBase = blockIdx.x * BN;

    const int lrow = lane >> 3;          // 0..7 : row within 8-row staging slab
    const int lcol = (lane & 7) * 8;     // 0..56: bf16 col offset (8 elems = 16B)

    const unsigned short* Ag = Abf + (size_t)rowBase * DIM;
    const unsigned short* Bg = Nbf + (size_t)colBase * DIM;

    f32x4 acc[4][4];
    #pragma unroll
    for (int i = 0; i < 4; i++)
        #pragma unroll
        for (int j = 0; j < 4; j++)
            acc[i][j] = (f32x4){0.f, 0.f, 0.f, 0.f};

    for (int k0 = 0; k0 < DIM; k0 += BK) {
        __syncthreads();  // prior iter's LDS reads done
        #pragma unroll
        for (int c = 0; c < 4; c++) {
            const int r0 = (w * 4 + c) * 8;   // 8-row slab; wave-uniform
            __builtin_amdgcn_global_load_lds(
                (const __attribute__((address_space(1))) void*)
                    (Ag + (size_t)(r0 + lrow) * DIM + k0 + lcol),
                (__attribute__((address_space(3))) void*)(As + r0 * BK),
                16, 0, 0);
            __builtin_amdgcn_global_load_lds(
                (const __attribute__((address_space(1))) void*)
                    (Bg + (size_t)(r0 + lrow) * DIM + k0 + lcol),
                (__attribute__((address_space(3))) void*)(Bs + r0 * BK),
                16, 0, 0);
        }
        __syncthreads();  // vmcnt drained by barrier semantics

        #pragma unroll
        for (int kk = 0; kk < BK; kk += 32) {
            short8 af[4], bfr[4];
            #pragma unroll
            for (int i = 0; i < 4; i++) {
                const int ar = wm * 64 + i * 16 + (lane & 15);
                af[i]  = *(const short8*)&As[ar * BK + kk + ((lane >> 4) * 8)];
                const int br = wn * 64 + i * 16 + (lane & 15);
                bfr[i] = *(const short8*)&Bs[br * BK + kk + ((lane >> 4) * 8)];
            }
            #pragma unroll
            for (int i = 0; i < 4; i++)
                #pragma unroll
                for (int j = 0; j < 4; j++)
                    acc[i][j] = __builtin_amdgcn_mfma_f32_16x16x32_bf16(
                        af[i], bfr[j], acc[i][j], 0, 0, 0);
        }
    }

    // Epilogue: per-row max over this wave's 64 columns, write one stripe value.
    // C/D layout (verified m89/m91): col = lane&15, row = (lane>>4)*4 + reg.
    const int stripe = blockIdx.x * 2 + wn;
    #pragma unroll
    for (int i = 0; i < 4; i++) {
        #pragma unroll
        for (int r = 0; r < 4; r++) {
            float v = fmaxf(fmaxf(acc[i][0][r], acc[i][1][r]),
                            fmaxf(acc[i][2][r], acc[i][3][r]));
            v = fmaxf(v, __shfl_xor(v, 1));
            v = fmaxf(v, __shfl_xor(v, 2));
            v = fmaxf(v, __shfl_xor(v, 4));
            v = fmaxf(v, __shfl_xor(v, 8));
            if ((lane & 15) == 0) {
                const int row = rowBase + wm * 64 + i * 16 + (lane >> 4) * 4 + r;
                partial[(size_t)row * 128 + stripe] = v;
            }
        }
    }
}

// ---------------- Kernel 3: stripe-max -> loss terms -> per-block partials --
// 64 blocks x 256 threads; block b covers rows [b*128, b*128+128).
// Each wave handles 32 rows; per-wave sums stay in registers (lane 0).
// NO global atomics (R2 post-mortem: 24576 same-address atomicAdds = 313 us).
__global__ __launch_bounds__(256) void reduce_kernel(
    const float* __restrict__ partial,
    const float* __restrict__ posdist,
    float* __restrict__ blockpart)   // [64][3]
{
    const int tid  = threadIdx.x;
    const int lane = tid & 63;
    const int w    = tid >> 6;
    __shared__ float red[4][3];

    float sloss = 0.f, spos = 0.f, shard = 0.f;

    #pragma unroll 4
    for (int i = 0; i < 32; i++) {
        const int row = blockIdx.x * 128 + w * 32 + i;
        float v = fmaxf(partial[(size_t)row * 128 + lane],
                        partial[(size_t)row * 128 + 64 + lane]);
        #pragma unroll
        for (int off = 1; off < 64; off <<= 1) v = fmaxf(v, __shfl_xor(v, off));
        if (lane == 0) {
            const float hard = (2.0f - 2.0f * v) * TINV;
            const float pos  = posdist[row];
            sloss += fmaxf(MARGIN + pos - hard, 0.0f);
            spos  += pos;
            shard += hard;
        }
    }
    if (lane == 0) { red[w][0] = sloss; red[w][1] = spos; red[w][2] = shard; }
    __syncthreads();
    if (tid == 0) {
        #pragma unroll
        for (int k = 0; k < 3; k++)
            blockpart[blockIdx.x * 3 + k] =
                red[0][k] + red[1][k] + red[2][k] + red[3][k];
    }
}

// ---------------- Kernel 4: finalize means (one wave, no atomics) -----------
__global__ __launch_bounds__(64) void finalize_kernel(
    const float* __restrict__ blockpart,
    float* __restrict__ out)
{
    const int lane = threadIdx.x;
    float a = blockpart[lane * 3 + 0];
    float b = blockpart[lane * 3 + 1];
    float c = blockpart[lane * 3 + 2];
    #pragma unroll
    for (int off = 1; off < 64; off <<= 1) {
        a += __shfl_xor(a, off);
        b += __shfl_xor(b, off);
        c += __shfl_xor(c, off);
    }
    if (lane == 0) {
        const float inv = 1.0f / (float)BS;
        out[0] = a * inv;
        out[1] = b * inv;
        out[2] = c * inv;
    }
}

extern "C" void kernel_launch(void* const* d_in, const int* in_sizes, int n_in,
                              void* d_out, int out_size, void* d_ws, size_t ws_size,
                              hipStream_t stream) {
    const float* feat = (const float*)d_in[0];
    char* ws = (char*)d_ws;

    // ws layout: Abf 16MiB | Nbf 16MiB | partial 4MiB | posdist 32KiB | blockpart
    unsigned short* Abf       = (unsigned short*)ws;
    unsigned short* Nbf       = (unsigned short*)(ws + ((size_t)16 << 20));
    float*          partial   = (float*)(ws + ((size_t)32 << 20));
    float*          posdist   = (float*)(ws + ((size_t)36 << 20));
    float*          blockpart = (float*)(ws + ((size_t)36 << 20) + 32768);

    normalize_kernel<<<BS, 256, 0, stream>>>(feat, Abf, Nbf, posdist);

    maxgemm_kernel<<<dim3(BS / BN, BS / BM), 256, 0, stream>>>(Abf, Nbf, partial);

    reduce_kernel<<<64, 256, 0, stream>>>(partial, posdist, blockpart);
    finalize_kernel<<<1, 64, 0, stream>>>(blockpart, (float*)d_out);
}

// Round 4
// 336.996 us; speedup vs baseline: 1.9863x; 1.0969x over previous
//
#include <hip/hip_runtime.h>

#define BS   8192
#define DIM  1024
#define TINV 10.0f    // 1 / TEMPERATURE
#define MARGIN 1.0f   // max(0.01, 1.0 - 0.1*0.0)

#define BM 128
#define BN 128
#define BK 64

typedef __attribute__((ext_vector_type(8))) short short8;
typedef __attribute__((ext_vector_type(4))) float f32x4;

__device__ __forceinline__ unsigned short f2bf(float f) {
    union { float f; unsigned int u; } v; v.f = f;
    unsigned int r = v.u + 0x7FFF + ((v.u >> 16) & 1);  // RNE
    return (unsigned short)(r >> 16);
}

// ---------------- Kernel 1: L2-normalize rows, emit bf16 A/N and posdist ----
__global__ __launch_bounds__(256) void normalize_kernel(
    const float* __restrict__ feat,
    unsigned short* __restrict__ Abf,
    unsigned short* __restrict__ Nbf,
    float* __restrict__ posdist)
{
    const int row  = blockIdx.x;
    const int tid  = threadIdx.x;
    const int lane = tid & 63;
    const int w    = tid >> 6;
    __shared__ float red[4][4];

    const float4* fo = (const float4*)(feat + (size_t)row * DIM);
    const float4* fp = (const float4*)(feat + (size_t)(BS + row) * DIM);
    const float4* fn = (const float4*)(feat + (size_t)(2 * BS + row) * DIM);
    float4 o = fo[tid], p = fp[tid], n = fn[tid];

    float so = o.x*o.x + o.y*o.y + o.z*o.z + o.w*o.w;
    float sp = p.x*p.x + p.y*p.y + p.z*p.z + p.w*p.w;
    float sn = n.x*n.x + n.y*n.y + n.z*n.z + n.w*n.w;
    #pragma unroll
    for (int off = 1; off < 64; off <<= 1) {
        so += __shfl_xor(so, off);
        sp += __shfl_xor(sp, off);
        sn += __shfl_xor(sn, off);
    }
    if (lane == 0) { red[w][0] = so; red[w][1] = sp; red[w][2] = sn; }
    __syncthreads();
    so = red[0][0] + red[1][0] + red[2][0] + red[3][0];
    sp = red[0][1] + red[1][1] + red[2][1] + red[3][1];
    sn = red[0][2] + red[1][2] + red[2][2] + red[3][2];

    const float io  = 1.0f / fmaxf(sqrtf(so), 1e-12f);
    const float ip  = 1.0f / fmaxf(sqrtf(sp), 1e-12f);
    const float in_ = 1.0f / fmaxf(sqrtf(sn), 1e-12f);

    float ax = o.x*io, ay = o.y*io, az = o.z*io, aw = o.w*io;
    float px = p.x*ip, py = p.y*ip, pz = p.z*ip, pw = p.w*ip;
    float nx = n.x*in_, ny = n.y*in_, nz = n.z*in_, nw = n.w*in_;

    ushort4 av; av.x = f2bf(ax); av.y = f2bf(ay); av.z = f2bf(az); av.w = f2bf(aw);
    ushort4 nv; nv.x = f2bf(nx); nv.y = f2bf(ny); nv.z = f2bf(nz); nv.w = f2bf(nw);
    ((ushort4*)(Abf + (size_t)row * DIM))[tid] = av;
    ((ushort4*)(Nbf + (size_t)row * DIM))[tid] = nv;

    float dx = ax - px, dy = ay - py, dz = az - pz, dw = aw - pw;
    float d = dx*dx + dy*dy + dz*dz + dw*dw;
    #pragma unroll
    for (int off = 1; off < 64; off <<= 1) d += __shfl_xor(d, off);
    if (lane == 0) red[w][3] = d;   // col 3: disjoint from cols 0..2 read above
    __syncthreads();
    if (tid == 0)
        posdist[row] = (red[0][3] + red[1][3] + red[2][3] + red[3][3]) * TINV;
}

// ---------------- Kernel 2: bf16 MFMA max-GEMM (C = A . N^T, row-max) -------
// LDS layout is XOR-swizzled: LDS(row r, 16B-chunk c) holds global chunk
// c ^ (r & 7) of row r. Row stride = 128 B = 32 banks, so without swizzle
// all rows alias bank-wise (R3: SQ_LDS_BANK_CONFLICT = 5e7 = 36% of cycles).
// With it, each read-octet (ar&7 = lane&7) spreads over all 8 bank groups.
__global__ __launch_bounds__(256) void maxgemm_kernel(
    const unsigned short* __restrict__ Abf,
    const unsigned short* __restrict__ Nbf,
    float* __restrict__ partial)   // [BS][128] row-major
{
    __shared__ unsigned short As[BM * BK];
    __shared__ unsigned short Bs[BN * BK];

    const int tid  = threadIdx.x;
    const int lane = tid & 63;
    const int w    = tid >> 6;
    const int wm   = w >> 1, wn = w & 1;
    const int rowBase = blockIdx.y * BM;
    const int colBase = blockIdx.x * BN;

    const int lrow = lane >> 3;                         // 0..7: row in slab
    const int gcol = ((lane & 7) ^ lrow) * 8;           // swizzled global chunk

    const unsigned short* Ag = Abf + (size_t)rowBase * DIM;
    const unsigned short* Bg = Nbf + (size_t)colBase * DIM;

    f32x4 acc[4][4];
    #pragma unroll
    for (int i = 0; i < 4; i++)
        #pragma unroll
        for (int j = 0; j < 4; j++)
            acc[i][j] = (f32x4){0.f, 0.f, 0.f, 0.f};

    for (int k0 = 0; k0 < DIM; k0 += BK) {
        __syncthreads();  // prior iter's LDS reads done
        #pragma unroll
        for (int c = 0; c < 4; c++) {
            const int r0 = (w * 4 + c) * 8;   // 8-row slab; wave-uniform
            __builtin_amdgcn_global_load_lds(
                (const __attribute__((address_space(1))) void*)
                    (Ag + (size_t)(r0 + lrow) * DIM + k0 + gcol),
                (__attribute__((address_space(3))) void*)(As + r0 * BK),
                16, 0, 0);
            __builtin_amdgcn_global_load_lds(
                (const __attribute__((address_space(1))) void*)
                    (Bg + (size_t)(r0 + lrow) * DIM + k0 + gcol),
                (__attribute__((address_space(3))) void*)(Bs + r0 * BK),
                16, 0, 0);
        }
        __syncthreads();  // vmcnt drained by barrier semantics

        #pragma unroll
        for (int kk = 0; kk < BK; kk += 32) {
            short8 af[4], bfr[4];
            const int kc = (kk >> 3) + (lane >> 4);   // 16B chunk index 0..7
            #pragma unroll
            for (int i = 0; i < 4; i++) {
                const int ar = wm * 64 + i * 16 + (lane & 15);
                af[i]  = *(const short8*)&As[ar * BK + ((kc ^ (ar & 7)) << 3)];
                const int br = wn * 64 + i * 16 + (lane & 15);
                bfr[i] = *(const short8*)&Bs[br * BK + ((kc ^ (br & 7)) << 3)];
            }
            #pragma unroll
            for (int i = 0; i < 4; i++)
                #pragma unroll
                for (int j = 0; j < 4; j++)
                    acc[i][j] = __builtin_amdgcn_mfma_f32_16x16x32_bf16(
                        af[i], bfr[j], acc[i][j], 0, 0, 0);
        }
    }

    // Epilogue: per-row max over this wave's 64 columns, write one stripe value.
    // C/D layout (verified m89/m91): col = lane&15, row = (lane>>4)*4 + reg.
    const int stripe = blockIdx.x * 2 + wn;
    #pragma unroll
    for (int i = 0; i < 4; i++) {
        #pragma unroll
        for (int r = 0; r < 4; r++) {
            float v = fmaxf(fmaxf(acc[i][0][r], acc[i][1][r]),
                            fmaxf(acc[i][2][r], acc[i][3][r]));
            v = fmaxf(v, __shfl_xor(v, 1));
            v = fmaxf(v, __shfl_xor(v, 2));
            v = fmaxf(v, __shfl_xor(v, 4));
            v = fmaxf(v, __shfl_xor(v, 8));
            if ((lane & 15) == 0) {
                const int row = rowBase + wm * 64 + i * 16 + (lane >> 4) * 4 + r;
                partial[(size_t)row * 128 + stripe] = v;
            }
        }
    }
}

// ---------------- Kernel 3: stripe-max -> loss terms -> per-block partials --
__global__ __launch_bounds__(256) void reduce_kernel(
    const float* __restrict__ partial,
    const float* __restrict__ posdist,
    float* __restrict__ blockpart)   // [64][3]
{
    const int tid  = threadIdx.x;
    const int lane = tid & 63;
    const int w    = tid >> 6;
    __shared__ float red[4][3];

    float sloss = 0.f, spos = 0.f, shard = 0.f;

    #pragma unroll 4
    for (int i = 0; i < 32; i++) {
        const int row = blockIdx.x * 128 + w * 32 + i;
        float v = fmaxf(partial[(size_t)row * 128 + lane],
                        partial[(size_t)row * 128 + 64 + lane]);
        #pragma unroll
        for (int off = 1; off < 64; off <<= 1) v = fmaxf(v, __shfl_xor(v, off));
        if (lane == 0) {
            const float hard = (2.0f - 2.0f * v) * TINV;
            const float pos  = posdist[row];
            sloss += fmaxf(MARGIN + pos - hard, 0.0f);
            spos  += pos;
            shard += hard;
        }
    }
    if (lane == 0) { red[w][0] = sloss; red[w][1] = spos; red[w][2] = shard; }
    __syncthreads();
    if (tid == 0) {
        #pragma unroll
        for (int k = 0; k < 3; k++)
            blockpart[blockIdx.x * 3 + k] =
                red[0][k] + red[1][k] + red[2][k] + red[3][k];
    }
}

// ---------------- Kernel 4: finalize means (one wave, no atomics) -----------
__global__ __launch_bounds__(64) void finalize_kernel(
    const float* __restrict__ blockpart,
    float* __restrict__ out)
{
    const int lane = threadIdx.x;
    float a = blockpart[lane * 3 + 0];
    float b = blockpart[lane * 3 + 1];
    float c = blockpart[lane * 3 + 2];
    #pragma unroll
    for (int off = 1; off < 64; off <<= 1) {
        a += __shfl_xor(a, off);
        b += __shfl_xor(b, off);
        c += __shfl_xor(c, off);
    }
    if (lane == 0) {
        const float inv = 1.0f / (float)BS;
        out[0] = a * inv;
        out[1] = b * inv;
        out[2] = c * inv;
    }
}

extern "C" void kernel_launch(void* const* d_in, const int* in_sizes, int n_in,
                              void* d_out, int out_size, void* d_ws, size_t ws_size,
                              hipStream_t stream) {
    const float* feat = (const float*)d_in[0];
    char* ws = (char*)d_ws;

    // ws layout: Abf 16MiB | Nbf 16MiB | partial 4MiB | posdist 32KiB | blockpart
    unsigned short* Abf       = (unsigned short*)ws;
    unsigned short* Nbf       = (unsigned short*)(ws + ((size_t)16 << 20));
    float*          partial   = (float*)(ws + ((size_t)32 << 20));
    float*          posdist   = (float*)(ws + ((size_t)36 << 20));
    float*          blockpart = (float*)(ws + ((size_t)36 << 20) + 32768);

    normalize_kernel<<<BS, 256, 0, stream>>>(feat, Abf, Nbf, posdist);

    maxgemm_kernel<<<dim3(BS / BN, BS / BM), 256, 0, stream>>>(Abf, Nbf, partial);

    reduce_kernel<<<64, 256, 0, stream>>>(partial, posdist, blockpart);
    finalize_kernel<<<1, 64, 0, stream>>>(blockpart, (float*)d_out);
}

// Round 5
// 317.926 us; speedup vs baseline: 2.1055x; 1.0600x over previous
//
#include <hip/hip_runtime.h>

#define BS   8192
#define DIM  1024
#define TINV 10.0f    // 1 / TEMPERATURE
#define MARGIN 1.0f   // max(0.01, 1.0 - 0.1*0.0)

#define BM  128
#define BN  128
#define BKB 128       // fp8 K-elements (= bytes) per staging iteration

// fp8 values are the normalized elements scaled by 16 -> dot = 256 * cos
#define QSCALE   16.0f
#define INV_QSQ  (1.0f / 256.0f)

typedef __attribute__((ext_vector_type(4))) float f32x4;
typedef __attribute__((ext_vector_type(4))) int   int4v;
typedef __attribute__((ext_vector_type(8))) int   int8v;

// ---------------- Kernel 1: L2-normalize rows, emit fp8(e4m3,x16) + posdist -
__global__ __launch_bounds__(256) void normalize_kernel(
    const float* __restrict__ feat,
    unsigned char* __restrict__ Afp8,
    unsigned char* __restrict__ Nfp8,
    float* __restrict__ posdist)
{
    const int row  = blockIdx.x;
    const int tid  = threadIdx.x;
    const int lane = tid & 63;
    const int w    = tid >> 6;
    __shared__ float red[4][4];

    const float4* fo = (const float4*)(feat + (size_t)row * DIM);
    const float4* fp = (const float4*)(feat + (size_t)(BS + row) * DIM);
    const float4* fn = (const float4*)(feat + (size_t)(2 * BS + row) * DIM);
    float4 o = fo[tid], p = fp[tid], n = fn[tid];

    float so = o.x*o.x + o.y*o.y + o.z*o.z + o.w*o.w;
    float sp = p.x*p.x + p.y*p.y + p.z*p.z + p.w*p.w;
    float sn = n.x*n.x + n.y*n.y + n.z*n.z + n.w*n.w;
    #pragma unroll
    for (int off = 1; off < 64; off <<= 1) {
        so += __shfl_xor(so, off);
        sp += __shfl_xor(sp, off);
        sn += __shfl_xor(sn, off);
    }
    if (lane == 0) { red[w][0] = so; red[w][1] = sp; red[w][2] = sn; }
    __syncthreads();
    so = red[0][0] + red[1][0] + red[2][0] + red[3][0];
    sp = red[0][1] + red[1][1] + red[2][1] + red[3][1];
    sn = red[0][2] + red[1][2] + red[2][2] + red[3][2];

    const float io  = 1.0f / fmaxf(sqrtf(so), 1e-12f);
    const float ip  = 1.0f / fmaxf(sqrtf(sp), 1e-12f);
    const float in_ = 1.0f / fmaxf(sqrtf(sn), 1e-12f);

    float ax = o.x*io, ay = o.y*io, az = o.z*io, aw = o.w*io;
    float px = p.x*ip, py = p.y*ip, pz = p.z*ip, pw = p.w*ip;
    float nx = n.x*in_, ny = n.y*in_, nz = n.z*in_, nw = n.w*in_;

    // e4m3 quantization with x16 pre-scale (avoids subnormals; max elem 16 << 448)
    int pa = __builtin_amdgcn_cvt_pk_fp8_f32(ax * QSCALE, ay * QSCALE, 0, false);
    pa     = __builtin_amdgcn_cvt_pk_fp8_f32(az * QSCALE, aw * QSCALE, pa, true);
    int pn = __builtin_amdgcn_cvt_pk_fp8_f32(nx * QSCALE, ny * QSCALE, 0, false);
    pn     = __builtin_amdgcn_cvt_pk_fp8_f32(nz * QSCALE, nw * QSCALE, pn, true);
    ((int*)(Afp8 + (size_t)row * DIM))[tid] = pa;
    ((int*)(Nfp8 + (size_t)row * DIM))[tid] = pn;

    float dx = ax - px, dy = ay - py, dz = az - pz, dw = aw - pw;
    float d = dx*dx + dy*dy + dz*dz + dw*dw;
    #pragma unroll
    for (int off = 1; off < 64; off <<= 1) d += __shfl_xor(d, off);
    if (lane == 0) red[w][3] = d;   // col 3: disjoint from cols 0..2 read above
    __syncthreads();
    if (tid == 0)
        posdist[row] = (red[0][3] + red[1][3] + red[2][3] + red[3][3]) * TINV;
}

// ---------------- Kernel 2: MX-fp8 MFMA max-GEMM (C = A . N^T, row-max) -----
// mfma_scale_f32_16x16x128_f8f6f4 with unit scales (E8M0 0x7F = 1.0).
// A-frag: row = lane&15, k = (lane>>4)*32 + j (32 contiguous fp8 bytes/lane)
// — gfx950's universal 16x16 pattern. C/D layout shape-determined (m127/m128).
// LDS rows are 128 B (= 32 banks), so the R4 XOR-chunk swizzle carries over:
// LDS(row r, 16B-chunk c) holds global chunk c ^ (r&7)  (R4: conflicts 5e7->0).
__global__ __launch_bounds__(256) void maxgemm_kernel(
    const unsigned char* __restrict__ Afp8,
    const unsigned char* __restrict__ Nfp8,
    float* __restrict__ partial)   // [BS][128] row-major
{
    __shared__ unsigned char As[BM * BKB];
    __shared__ unsigned char Bs[BN * BKB];

    const int tid  = threadIdx.x;
    const int lane = tid & 63;
    const int w    = tid >> 6;
    const int wm   = w >> 1, wn = w & 1;
    const int rowBase = blockIdx.y * BM;
    const int colBase = blockIdx.x * BN;

    const int lrow = lane >> 3;                      // 0..7: row in 8-row slab
    const int gcol = ((lane & 7) ^ lrow) * 16;       // swizzled 16B chunk (bytes)

    const unsigned char* Ag = Afp8 + (size_t)rowBase * DIM;
    const unsigned char* Bg = Nfp8 + (size_t)colBase * DIM;

    f32x4 acc[4][4];
    #pragma unroll
    for (int i = 0; i < 4; i++)
        #pragma unroll
        for (int j = 0; j < 4; j++)
            acc[i][j] = (f32x4){0.f, 0.f, 0.f, 0.f};

    for (int k0 = 0; k0 < DIM; k0 += BKB) {
        __syncthreads();  // prior iter's LDS reads done
        #pragma unroll
        for (int c = 0; c < 4; c++) {
            const int r0 = (w * 4 + c) * 8;   // 8-row slab; wave-uniform
            __builtin_amdgcn_global_load_lds(
                (const __attribute__((address_space(1))) void*)
                    (Ag + (size_t)(r0 + lrow) * DIM + k0 + gcol),
                (__attribute__((address_space(3))) void*)(As + r0 * BKB),
                16, 0, 0);
            __builtin_amdgcn_global_load_lds(
                (const __attribute__((address_space(1))) void*)
                    (Bg + (size_t)(r0 + lrow) * DIM + k0 + gcol),
                (__attribute__((address_space(3))) void*)(Bs + r0 * BKB),
                16, 0, 0);
        }
        __syncthreads();  // vmcnt drained by barrier semantics

        const int q2 = (lane >> 4) * 2;   // first of this quad's two 16B chunks
        int8v af[4], bfr[4];
        #pragma unroll
        for (int i = 0; i < 4; i++) {
            const int ar = wm * 64 + i * 16 + (lane & 15);
            const unsigned char* pa = As + ar * BKB;
            int4v alo = *(const int4v*)(pa + ((q2 ^ (ar & 7)) << 4));
            int4v ahi = *(const int4v*)(pa + (((q2 + 1) ^ (ar & 7)) << 4));
            af[i] = (int8v){alo[0], alo[1], alo[2], alo[3],
                            ahi[0], ahi[1], ahi[2], ahi[3]};
            const int br = wn * 64 + i * 16 + (lane & 15);
            const unsigned char* pb = Bs + br * BKB;
            int4v blo = *(const int4v*)(pb + ((q2 ^ (br & 7)) << 4));
            int4v bhi = *(const int4v*)(pb + (((q2 + 1) ^ (br & 7)) << 4));
            bfr[i] = (int8v){blo[0], blo[1], blo[2], blo[3],
                             bhi[0], bhi[1], bhi[2], bhi[3]};
        }
        #pragma unroll
        for (int i = 0; i < 4; i++)
            #pragma unroll
            for (int j = 0; j < 4; j++)
                acc[i][j] = __builtin_amdgcn_mfma_scale_f32_16x16x128_f8f6f4(
                    af[i], bfr[j], acc[i][j],
                    0, 0,               // cbsz=FP8(e4m3), blgp=FP8(e4m3)
                    0, 0x7F7F7F7F,      // opselA, scaleA = 1.0
                    0, 0x7F7F7F7F);     // opselB, scaleB = 1.0
    }

    // Epilogue: per-row max over this wave's 64 columns, write one stripe value.
    // C/D layout (verified m89/m91): col = lane&15, row = (lane>>4)*4 + reg.
    const int stripe = blockIdx.x * 2 + wn;
    #pragma unroll
    for (int i = 0; i < 4; i++) {
        #pragma unroll
        for (int r = 0; r < 4; r++) {
            float v = fmaxf(fmaxf(acc[i][0][r], acc[i][1][r]),
                            fmaxf(acc[i][2][r], acc[i][3][r]));
            v = fmaxf(v, __shfl_xor(v, 1));
            v = fmaxf(v, __shfl_xor(v, 2));
            v = fmaxf(v, __shfl_xor(v, 4));
            v = fmaxf(v, __shfl_xor(v, 8));
            if ((lane & 15) == 0) {
                const int row = rowBase + wm * 64 + i * 16 + (lane >> 4) * 4 + r;
                partial[(size_t)row * 128 + stripe] = v;   // = 256 * cos
            }
        }
    }
}

// ---------------- Kernel 3: stripe-max -> loss terms -> per-block partials --
__global__ __launch_bounds__(256) void reduce_kernel(
    const float* __restrict__ partial,
    const float* __restrict__ posdist,
    float* __restrict__ blockpart)   // [64][3]
{
    const int tid  = threadIdx.x;
    const int lane = tid & 63;
    const int w    = tid >> 6;
    __shared__ float red[4][3];

    float sloss = 0.f, spos = 0.f, shard = 0.f;

    #pragma unroll 4
    for (int i = 0; i < 32; i++) {
        const int row = blockIdx.x * 128 + w * 32 + i;
        float v = fmaxf(partial[(size_t)row * 128 + lane],
                        partial[(size_t)row * 128 + 64 + lane]);
        #pragma unroll
        for (int off = 1; off < 64; off <<= 1) v = fmaxf(v, __shfl_xor(v, off));
        if (lane == 0) {
            // v = 256*cos  ->  hard = (2 - 2*cos)/T = (2 - v/128)*TINV
            const float hard = (2.0f - 2.0f * v * INV_QSQ) * TINV;
            const float pos  = posdist[row];
            sloss += fmaxf(MARGIN + pos - hard, 0.0f);
            spos  += pos;
            shard += hard;
        }
    }
    if (lane == 0) { red[w][0] = sloss; red[w][1] = spos; red[w][2] = shard; }
    __syncthreads();
    if (tid == 0) {
        #pragma unroll
        for (int k = 0; k < 3; k++)
            blockpart[blockIdx.x * 3 + k] =
                red[0][k] + red[1][k] + red[2][k] + red[3][k];
    }
}

// ---------------- Kernel 4: finalize means (one wave, no atomics) -----------
__global__ __launch_bounds__(64) void finalize_kernel(
    const float* __restrict__ blockpart,
    float* __restrict__ out)
{
    const int lane = threadIdx.x;
    float a = blockpart[lane * 3 + 0];
    float b = blockpart[lane * 3 + 1];
    float c = blockpart[lane * 3 + 2];
    #pragma unroll
    for (int off = 1; off < 64; off <<= 1) {
        a += __shfl_xor(a, off);
        b += __shfl_xor(b, off);
        c += __shfl_xor(c, off);
    }
    if (lane == 0) {
        const float inv = 1.0f / (float)BS;
        out[0] = a * inv;
        out[1] = b * inv;
        out[2] = c * inv;
    }
}

extern "C" void kernel_launch(void* const* d_in, const int* in_sizes, int n_in,
                              void* d_out, int out_size, void* d_ws, size_t ws_size,
                              hipStream_t stream) {
    const float* feat = (const float*)d_in[0];
    char* ws = (char*)d_ws;

    // ws layout: Afp8 8MiB | Nfp8 8MiB | partial 4MiB | posdist 32KiB | blockpart
    unsigned char* Afp8      = (unsigned char*)ws;
    unsigned char* Nfp8      = (unsigned char*)(ws + ((size_t)8 << 20));
    float*         partial   = (float*)(ws + ((size_t)16 << 20));
    float*         posdist   = (float*)(ws + ((size_t)20 << 20));
    float*         blockpart = (float*)(ws + ((size_t)20 << 20) + 32768);

    normalize_kernel<<<BS, 256, 0, stream>>>(feat, Afp8, Nfp8, posdist);

    maxgemm_kernel<<<dim3(BS / BN, BS / BM), 256, 0, stream>>>(Afp8, Nfp8, partial);

    reduce_kernel<<<64, 256, 0, stream>>>(partial, posdist, blockpart);
    finalize_kernel<<<1, 64, 0, stream>>>(blockpart, (float*)d_out);
}